// Round 10
// baseline (194.564 us; speedup 1.0000x reference)
//
#include <hip/hip_runtime.h>

#define N_NODES 50000
#define N_EDGES 800000
#define N_GRAPHS 512
#define D 64

typedef unsigned short bfu;

__device__ __forceinline__ float bf2f(bfu u) {
    return __uint_as_float(((unsigned)u) << 16);
}
__device__ __forceinline__ bfu f2bf(float f) {
    unsigned x = __float_as_uint(f);
    unsigned r = (x + 0x7fffu + ((x >> 16) & 1u)) >> 16;   // RNE
    return (bfu)r;
}

// ---------------- prep: zero deg + gstart + feat->bf16, one kernel ----------
__global__ __launch_bounds__(256) void prep_conv_kernel(
    const float* __restrict__ feat, const int* __restrict__ batch,
    int* __restrict__ deg, int* __restrict__ start, bfu* __restrict__ xb)
{
    int i = blockIdx.x * 256 + threadIdx.x;
    float4 v = ((const float4*)feat)[i];
    ushort4 o;
    o.x = f2bf(v.x); o.y = f2bf(v.y); o.z = f2bf(v.z); o.w = f2bf(v.w);
    ((ushort4*)xb)[i] = o;
    if (i < N_NODES / 4)
        ((int4*)deg)[i] = make_int4(0, 0, 0, 0);
    if (i < N_NODES) {
        int g = batch[i];
        int gp = (i == 0) ? -1 : batch[i - 1];
        for (int gg = gp + 1; gg <= g; ++gg) start[gg] = i;
        if (i == N_NODES - 1)
            for (int gg = g + 1; gg <= N_GRAPHS; ++gg) start[gg] = N_NODES;
    }
}

// ---------------- CSR build: hist+rank with 4 edges/thread (ILP) ----------
// The returning atomicAdd is a ~700ns round trip; 4 independent atomics per
// thread quadruple the latency hiding (single vmcnt wait for all 4).
__global__ __launch_bounds__(256) void hist_rank_kernel(
    const int* __restrict__ dst, int* __restrict__ deg, int* __restrict__ rank)
{
    int base = (blockIdx.x * 256 + threadIdx.x) * 4;
    if (base + 4 <= N_EDGES) {
        int4 d4 = *(const int4*)(dst + base);
        int r0 = atomicAdd(&deg[d4.x], 1);
        int r1 = atomicAdd(&deg[d4.y], 1);
        int r2 = atomicAdd(&deg[d4.z], 1);
        int r3 = atomicAdd(&deg[d4.w], 1);
        *(int4*)(rank + base) = make_int4(r0, r1, r2, r3);
    } else {
        for (int e = base; e < N_EDGES; ++e)
            rank[e] = atomicAdd(&deg[dst[e]], 1);
    }
}

__global__ __launch_bounds__(256) void scan1_kernel(
    const int* __restrict__ deg, int* __restrict__ excl,
    int* __restrict__ bsum, int n)
{
    __shared__ int s[256];
    int t = threadIdx.x;
    int i = blockIdx.x * 256 + t;
    int v = (i < n) ? deg[i] : 0;
    s[t] = v;
    __syncthreads();
    for (int off = 1; off < 256; off <<= 1) {
        int x = (t >= off) ? s[t - off] : 0;
        __syncthreads();
        s[t] += x;
        __syncthreads();
    }
    if (i < n) excl[i] = s[t] - v;
    if (t == 255) bsum[blockIdx.x] = s[255];
}

__global__ __launch_bounds__(256) void scan2_kernel(
    const int* __restrict__ bsum, int* __restrict__ boffs, int nblocks)
{
    __shared__ int s[256];
    int t = threadIdx.x;
    int v = (t < nblocks) ? bsum[t] : 0;
    s[t] = v;
    __syncthreads();
    for (int off = 1; off < 256; off <<= 1) {
        int x = (t >= off) ? s[t - off] : 0;
        __syncthreads();
        s[t] += x;
        __syncthreads();
    }
    if (t < nblocks) boffs[t] = s[t] - v;
}

__global__ __launch_bounds__(256) void scan3_kernel(
    int* __restrict__ rowptr, const int* __restrict__ boffs, int n)
{
    int i = blockIdx.x * 256 + threadIdx.x;
    if (i < n) rowptr[i] += boffs[blockIdx.x];
    if (blockIdx.x == 0 && threadIdx.x == 0) rowptr[n] = N_EDGES;
}

// Non-atomic fill, 4 edges/thread: 4 independent rowptr-gathers + scatter
// stores in flight.
__global__ __launch_bounds__(256) void fill_scatter_kernel(
    const int* __restrict__ src, const int* __restrict__ dst,
    const int* __restrict__ rank, const int* __restrict__ rowptr,
    int* __restrict__ eidx)
{
    int base = (blockIdx.x * 256 + threadIdx.x) * 4;
    if (base + 4 <= N_EDGES) {
        int4 d4 = *(const int4*)(dst + base);
        int4 r4 = *(const int4*)(rank + base);
        int4 s4 = *(const int4*)(src + base);
        int p0 = rowptr[d4.x] + r4.x;
        int p1 = rowptr[d4.y] + r4.y;
        int p2 = rowptr[d4.z] + r4.z;
        int p3 = rowptr[d4.w] + r4.w;
        eidx[p0] = s4.x;
        eidx[p1] = s4.y;
        eidx[p2] = s4.z;
        eidx[p3] = s4.w;
    } else {
        for (int e = base; e < N_EDGES; ++e)
            eidx[rowptr[dst[e]] + rank[e]] = src[e];
    }
}

// ---------------- gather: 4 nodes per WAVE (16 lanes x ushort4 per row) -----
__global__ __launch_bounds__(256) void gather_kernel(
    const bfu* __restrict__ xb, const int* __restrict__ rowptr,
    const int* __restrict__ eidx, float* __restrict__ agg)
{
    const int t = blockIdx.x * 256 + threadIdx.x;
    const int lane = threadIdx.x & 63;
    const int g = lane >> 4;        // node group 0..3 within wave
    const int q = lane & 15;        // ushort4 slice 0..15
    const int n = (t >> 6) * 4 + g; // node id (12500 waves x 4 = 50000 exact)

    const ushort4* xrow = (const ushort4*)(xb + (size_t)n * D);
    ushort4 v0 = xrow[q];
    float a0 = bf2f(v0.x), a1 = bf2f(v0.y), a2 = bf2f(v0.z), a3 = bf2f(v0.w);

    const int e1 = rowptr[n + 1];
    int e = rowptr[n];
    for (; e + 4 <= e1; e += 4) {
        int s0 = eidx[e + 0], s1 = eidx[e + 1];
        int s2 = eidx[e + 2], s3 = eidx[e + 3];
        ushort4 r0 = ((const ushort4*)(xb + (size_t)s0 * D))[q];
        ushort4 r1 = ((const ushort4*)(xb + (size_t)s1 * D))[q];
        ushort4 r2 = ((const ushort4*)(xb + (size_t)s2 * D))[q];
        ushort4 r3 = ((const ushort4*)(xb + (size_t)s3 * D))[q];
        a0 += (bf2f(r0.x) + bf2f(r1.x)) + (bf2f(r2.x) + bf2f(r3.x));
        a1 += (bf2f(r0.y) + bf2f(r1.y)) + (bf2f(r2.y) + bf2f(r3.y));
        a2 += (bf2f(r0.z) + bf2f(r1.z)) + (bf2f(r2.z) + bf2f(r3.z));
        a3 += (bf2f(r0.w) + bf2f(r1.w)) + (bf2f(r2.w) + bf2f(r3.w));
    }
    for (; e < e1; ++e) {
        ushort4 r = ((const ushort4*)(xb + (size_t)eidx[e] * D))[q];
        a0 += bf2f(r.x); a1 += bf2f(r.y); a2 += bf2f(r.z); a3 += bf2f(r.w);
    }
    ((float4*)agg)[(size_t)n * 16 + q] = make_float4(a0, a1, a2, a3);
}

// ---------------- MLP: y = relu(relu(agg@wa+ba)@wb+bb) ----------------
template <int OUT_BF16>
__global__ __launch_bounds__(256) void mlp_kernel(
    const float* __restrict__ agg,
    const float* __restrict__ wa, const float* __restrict__ ba,
    const float* __restrict__ wb, const float* __restrict__ bb,
    void* __restrict__ xout)
{
    __shared__ float sX[D][D];   // [k][n], then [hk][n]
    __shared__ float sW[D][D];   // [k][od]: Wa, then Wb
    const int t = threadIdx.x;
    const int n0 = blockIdx.x * 64;

    float4 wbr[4];
    #pragma unroll
    for (int c = 0; c < 4; ++c) {
        wbr[c] = ((const float4*)wb)[t + c * 256];
        ((float4*)sW)[t + c * 256] = ((const float4*)wa)[t + c * 256];
    }

    {
        int n = t & 63;
        int kq = t >> 6;
        int gn = n0 + n;
        #pragma unroll
        for (int c = 0; c < 4; ++c) {
            float4 v = make_float4(0.f, 0.f, 0.f, 0.f);
            if (gn < N_NODES)
                v = ((const float4*)agg)[(size_t)gn * 16 + kq * 4 + c];
            int k = kq * 16 + c * 4;
            sX[k + 0][n] = v.x;
            sX[k + 1][n] = v.y;
            sX[k + 2][n] = v.z;
            sX[k + 3][n] = v.w;
        }
    }
    __syncthreads();

    const int tn4 = (t & 15) * 4;
    const int tod = t >> 4;
    const int tod4 = tod * 4;

    float acc[4][4];
    {
        float4 bav = ((const float4*)ba)[tod];
        #pragma unroll
        for (int i = 0; i < 4; ++i) {
            acc[i][0] = bav.x; acc[i][1] = bav.y;
            acc[i][2] = bav.z; acc[i][3] = bav.w;
        }
    }
    #pragma unroll 4
    for (int k = 0; k < D; ++k) {
        const float4 xf = *(const float4*)(&sX[k][tn4]);
        const float4 wf = *(const float4*)(&sW[k][tod4]);
        const float xv[4] = {xf.x, xf.y, xf.z, xf.w};
        const float wv[4] = {wf.x, wf.y, wf.z, wf.w};
        #pragma unroll
        for (int i = 0; i < 4; ++i)
            #pragma unroll
            for (int j = 0; j < 4; ++j)
                acc[i][j] = fmaf(xv[i], wv[j], acc[i][j]);
    }
    __syncthreads();

    #pragma unroll
    for (int j = 0; j < 4; ++j) {
        float4 hv = make_float4(fmaxf(acc[0][j], 0.f), fmaxf(acc[1][j], 0.f),
                                fmaxf(acc[2][j], 0.f), fmaxf(acc[3][j], 0.f));
        *(float4*)(&sX[tod4 + j][tn4]) = hv;
    }
    #pragma unroll
    for (int c = 0; c < 4; ++c)
        ((float4*)sW)[t + c * 256] = wbr[c];
    __syncthreads();

    {
        float4 bbv = ((const float4*)bb)[tod];
        #pragma unroll
        for (int i = 0; i < 4; ++i) {
            acc[i][0] = bbv.x; acc[i][1] = bbv.y;
            acc[i][2] = bbv.z; acc[i][3] = bbv.w;
        }
    }
    #pragma unroll 4
    for (int k = 0; k < D; ++k) {
        const float4 xf = *(const float4*)(&sX[k][tn4]);
        const float4 wf = *(const float4*)(&sW[k][tod4]);
        const float xv[4] = {xf.x, xf.y, xf.z, xf.w};
        const float wv[4] = {wf.x, wf.y, wf.z, wf.w};
        #pragma unroll
        for (int i = 0; i < 4; ++i)
            #pragma unroll
            for (int j = 0; j < 4; ++j)
                acc[i][j] = fmaf(xv[i], wv[j], acc[i][j]);
    }

    #pragma unroll
    for (int i = 0; i < 4; ++i) {
        int gn = n0 + tn4 + i;
        if (gn < N_NODES) {
            float o0 = fmaxf(acc[i][0], 0.f), o1 = fmaxf(acc[i][1], 0.f);
            float o2 = fmaxf(acc[i][2], 0.f), o3 = fmaxf(acc[i][3], 0.f);
            if (OUT_BF16) {
                ushort4 ov;
                ov.x = f2bf(o0); ov.y = f2bf(o1); ov.z = f2bf(o2); ov.w = f2bf(o3);
                ((ushort4*)xout)[(size_t)gn * 16 + tod] = ov;
            } else {
                ((float4*)xout)[(size_t)gn * 16 + tod] =
                    make_float4(o0, o1, o2, o3);
            }
        }
    }
}

// ---------------- pool + final linear ----------------
__global__ __launch_bounds__(64) void pool_kernel(
    const float* __restrict__ xf, const int* __restrict__ start,
    const float* __restrict__ wl, const float* __restrict__ bl,
    float* __restrict__ out)
{
    int g = blockIdx.x, d = threadIdx.x;
    int s = start[g], e = start[g + 1];
    float sum = 0.f;
    int i = s;
    for (; i + 4 <= e; i += 4) {
        float a = xf[(size_t)(i + 0) * D + d];
        float b = xf[(size_t)(i + 1) * D + d];
        float c = xf[(size_t)(i + 2) * D + d];
        float dd = xf[(size_t)(i + 3) * D + d];
        sum += (a + b) + (c + dd);
    }
    for (; i < e; ++i) sum += xf[(size_t)i * D + d];
    float c = fmaxf((float)(e - s), 1.0f);
    float v = (sum / c) * wl[d];
    for (int off = 32; off > 0; off >>= 1)
        v += __shfl_down(v, off, 64);
    if (d == 0) out[g] = v + bl[0];
}

extern "C" void kernel_launch(void* const* d_in, const int* in_sizes, int n_in,
                              void* d_out, int out_size, void* d_ws, size_t ws_size,
                              hipStream_t stream) {
    const float* feat  = (const float*)d_in[0];
    const int*   ei    = (const int*)d_in[1];
    const int*   batch = (const int*)d_in[2];
    const float* w1a = (const float*)d_in[3];
    const float* b1a = (const float*)d_in[4];
    const float* w1b = (const float*)d_in[5];
    const float* b1b = (const float*)d_in[6];
    const float* w2a = (const float*)d_in[7];
    const float* b2a = (const float*)d_in[8];
    const float* w2b = (const float*)d_in[9];
    const float* b2b = (const float*)d_in[10];
    const float* w3a = (const float*)d_in[11];
    const float* b3a = (const float*)d_in[12];
    const float* w3b = (const float*)d_in[13];
    const float* b3b = (const float*)d_in[14];
    const float* wl  = (const float*)d_in[15];
    const float* bl  = (const float*)d_in[16];
    const int* src = ei;
    const int* dst = ei + N_EDGES;

    char* w = (char*)d_ws;
    float* agg    = (float*)w;  w += (size_t)N_NODES * D * sizeof(float);
    float* buf0   = (float*)w;  w += (size_t)N_NODES * D * sizeof(float);
    bfu*   xb     = (bfu*)w;    w += (size_t)N_NODES * D * sizeof(bfu);
    int*   rowptr = (int*)w;    w += (size_t)(N_NODES + 1) * sizeof(int);
    int*   deg    = (int*)w;    w += (size_t)N_NODES * sizeof(int);
    int*   rank   = (int*)w;    w += (size_t)N_EDGES * sizeof(int);
    int*   eidx   = (int*)w;    w += (size_t)N_EDGES * sizeof(int);
    int*   bsum   = (int*)w;    w += 256 * sizeof(int);
    int*   boffs  = (int*)w;    w += 256 * sizeof(int);
    int*   start  = (int*)w;    w += (size_t)(N_GRAPHS + 1) * sizeof(int);
    float* out    = (float*)d_out;

    const int scanBlocks = (N_NODES + 255) / 256;         // 196
    const int edgeGrid   = (N_EDGES + 255) / 256;         // 3125
    const int edge4Grid  = (N_EDGES / 4 + 255) / 256;     // 782 (4 edges/thr)
    const int gatherGrid = N_NODES / 16;                  // 3125 (4 nodes/wave)
    const int mlpGrid    = (N_NODES + 63) / 64;           // 782

    prep_conv_kernel<<<edgeGrid, 256, 0, stream>>>(feat, batch, deg, start, xb);
    hist_rank_kernel<<<edge4Grid, 256, 0, stream>>>(dst, deg, rank);
    scan1_kernel<<<scanBlocks, 256, 0, stream>>>(deg, rowptr, bsum, N_NODES);
    scan2_kernel<<<1, 256, 0, stream>>>(bsum, boffs, scanBlocks);
    scan3_kernel<<<scanBlocks, 256, 0, stream>>>(rowptr, boffs, N_NODES);
    fill_scatter_kernel<<<edge4Grid, 256, 0, stream>>>(src, dst, rank, rowptr, eidx);

    // layer 1
    gather_kernel<<<gatherGrid, 256, 0, stream>>>(xb, rowptr, eidx, agg);
    mlp_kernel<1><<<mlpGrid, 256, 0, stream>>>(agg, w1a, b1a, w1b, b1b, xb);
    // layer 2
    gather_kernel<<<gatherGrid, 256, 0, stream>>>(xb, rowptr, eidx, agg);
    mlp_kernel<1><<<mlpGrid, 256, 0, stream>>>(agg, w2a, b2a, w2b, b2b, xb);
    // layer 3
    gather_kernel<<<gatherGrid, 256, 0, stream>>>(xb, rowptr, eidx, agg);
    mlp_kernel<0><<<mlpGrid, 256, 0, stream>>>(agg, w3a, b3a, w3b, b3b, buf0);

    pool_kernel<<<N_GRAPHS, dim3(64), 0, stream>>>(buf0, start, wl, bl, out);
}